// Round 12
// baseline (825.606 us; speedup 1.0000x reference)
//
#include <hip/hip_runtime.h>

static constexpr int NN = 100000;   // nodes
static constexpr int NE = 1600000;  // edges
static constexpr int NB = 256;     // graphs
static constexpr int NO = 32;      // orders per graph
static constexpr int HD = 128;     // hidden dim
static constexpr long NH = (long)NN * HD;

static constexpr int BSHIFT = 9;                 // bucket = dst >> 9
static constexpr int BSIZE = 1 << BSHIFT;        // 512 nodes per bucket
static constexpr int NBUCK = 256;
static constexpr int CHUNK = 16384;
static constexpr int NCHUNK = (NE + CHUNK - 1) / CHUNK;  // 98
static constexpr int POOL_ROWS = 64;
static constexpr int POOL_GRID = (NN + POOL_ROWS - 1) / POOL_ROWS;  // 1563
static constexpr int NSUB = 64;                  // BN stat sub-accumulators

typedef _Float16 f16x8 __attribute__((ext_vector_type(8)));
typedef _Float16 f16x4 __attribute__((ext_vector_type(4)));
typedef _Float16 f16x2 __attribute__((ext_vector_type(2)));
typedef float f32x4 __attribute__((ext_vector_type(4)));

__device__ __forceinline__ unsigned int encf(float f) {
  unsigned int u = __float_as_uint(f);
  return (u & 0x80000000u) ? ~u : (u | 0x80000000u);
}
__device__ __forceinline__ float decf(unsigned int e) {
  return (e & 0x80000000u) ? __uint_as_float(e & 0x7fffffffu) : __uint_as_float(~e);
}

// ================= CSR build: two-level locality-aware counting sort =================
__global__ void bucket_count(const int* __restrict__ ei, int* __restrict__ bucketTotal) {
  __shared__ int cnt[NBUCK];
  const int t = threadIdx.x;  // 256
  cnt[t] = 0;
  __syncthreads();
  long start = (long)blockIdx.x * CHUNK;
  long end = min((long)NE, start + CHUNK);
  for (long e = start + t; e < end; e += 256)
    atomicAdd(&cnt[ei[NE + e] >> BSHIFT], 1);
  __syncthreads();
  if (cnt[t]) atomicAdd(&bucketTotal[t], cnt[t]);
}

__global__ void bucket_scan(const int* __restrict__ bucketTotal, int* __restrict__ bucketBase,
                            int* __restrict__ cursor) {
  __shared__ int part[NBUCK];
  const int t = threadIdx.x;  // 256
  int v = bucketTotal[t];
  part[t] = v;
  __syncthreads();
  for (int off = 1; off < NBUCK; off <<= 1) {
    int u = (t >= off) ? part[t - off] : 0;
    __syncthreads();
    part[t] += u;
    __syncthreads();
  }
  int base = part[t] - v;
  bucketBase[t] = base;
  cursor[t] = base;
  if (t == NBUCK - 1) bucketBase[NBUCK] = part[t];
}

__global__ void bucket_scatter(const int* __restrict__ ei, int* __restrict__ cursor,
                               unsigned int* __restrict__ binned) {
  __shared__ int cnt[NBUCK];
  __shared__ int runbase[NBUCK];
  const int t = threadIdx.x;  // 256
  cnt[t] = 0;
  __syncthreads();
  long start = (long)blockIdx.x * CHUNK;
  long end = min((long)NE, start + CHUNK);
  for (long e = start + t; e < end; e += 256)
    atomicAdd(&cnt[ei[NE + e] >> BSHIFT], 1);
  __syncthreads();
  int c = cnt[t];
  runbase[t] = c ? atomicAdd(&cursor[t], c) : 0;
  cnt[t] = 0;  // reuse as local run cursor
  __syncthreads();
  for (long e = start + t; e < end; e += 256) {
    int d = ei[NE + e], s = ei[e];
    int b = d >> BSHIFT;
    int pos = runbase[b] + atomicAdd(&cnt[b], 1);
    binned[pos] = ((unsigned int)s << BSHIFT) | (unsigned int)(d & (BSIZE - 1));
  }
}

__global__ void bucket_csr(const unsigned int* __restrict__ binned,
                           const int* __restrict__ bucketBase,
                           int* __restrict__ rowptr, int* __restrict__ col) {
  __shared__ int cnt[BSIZE];
  __shared__ int excl[BSIZE];
  __shared__ int cur[BSIZE];
  __shared__ int part[256];
  const int b = blockIdx.x;
  const int t = threadIdx.x;  // 256
  const int lo = bucketBase[b], hi = bucketBase[b + 1];
  cnt[t] = 0; cnt[t + 256] = 0;
  __syncthreads();
  for (int i = lo + t; i < hi; i += 256)
    atomicAdd(&cnt[binned[i] & (BSIZE - 1)], 1);
  __syncthreads();
  int a0 = cnt[2 * t], a1 = cnt[2 * t + 1];
  int s = a0 + a1;
  part[t] = s;
  __syncthreads();
  for (int off = 1; off < 256; off <<= 1) {
    int u = (t >= off) ? part[t - off] : 0;
    __syncthreads();
    part[t] += u;
    __syncthreads();
  }
  int ebase = part[t] - s;
  excl[2 * t] = ebase;
  excl[2 * t + 1] = ebase + a0;
  __syncthreads();
  const int node0 = b * BSIZE;
  for (int i = t; i < BSIZE; i += 256) {
    int node = node0 + i;
    if (node < NN) rowptr[node] = lo + excl[i] + cnt[i];  // inclusive end
    cur[i] = lo + excl[i];
  }
  __syncthreads();
  for (int i = lo + t; i < hi; i += 256) {
    unsigned int v = binned[i];
    int pos = atomicAdd(&cur[v & (BSIZE - 1)], 1);
    col[pos] = (int)(v >> BSHIFT);
  }
}

// ---------------- x fp32 -> fp16, once ----------------
__global__ void f32to16_kernel(const float* __restrict__ in, _Float16* __restrict__ out) {
  long i = (long)(blockIdx.x * 256 + threadIdx.x) * 8;
  if (i >= NH) return;
  float4 a = *reinterpret_cast<const float4*>(in + i);
  float4 b = *reinterpret_cast<const float4*>(in + i + 4);
  f16x8 v;
  v[0] = (_Float16)a.x; v[1] = (_Float16)a.y; v[2] = (_Float16)a.z; v[3] = (_Float16)a.w;
  v[4] = (_Float16)b.x; v[5] = (_Float16)b.y; v[6] = (_Float16)b.z; v[7] = (_Float16)b.w;
  *reinterpret_cast<f16x8*>(out + i) = v;
}

// ---------------- weight packing: fp32 W[128][128] -> fp16 MFMA B-fragments (GIN) ----------------
__global__ void pack_w_kernel(const float* __restrict__ gW1, const float* __restrict__ gW2,
                              _Float16* __restrict__ Wp) {
  int tid = blockIdx.x * blockDim.x + threadIdx.x;  // 3*2*8*4*64 = 12288
  if (tid >= 12288) return;
  int lane = tid & 63;
  int s = (tid >> 6) & 3;
  int t = (tid >> 8) & 7;
  int which = (tid >> 11) & 1;
  int layer = tid >> 12;
  const float* W = (which ? gW2 : gW1) + (long)layer * 128 * 128;
  _Float16* dst = Wp + (long)tid * 8;
  int kbase = s * 32 + ((lane >> 4) << 3);
  int n = t * 16 + (lane & 15);
#pragma unroll
  for (int j = 0; j < 8; ++j) dst[j] = (_Float16)W[(kbase + j) * 128 + n];
}

// ---------------- head weight packing ----------------
__global__ void pack_head_kernel(const float* __restrict__ oW1, const float* __restrict__ oW2,
                                 const float* __restrict__ sW1, const float* __restrict__ sW2,
                                 _Float16* __restrict__ dst) {
  int tid = blockIdx.x * blockDim.x + threadIdx.x;  // 5632 total
  if (tid >= 5632) return;
  const float* W; int K, N, rowOff;
  int base = tid;
  if (tid < 512)       { W = oW1; K = 32;  N = 128; rowOff = 0;   }
  else if (tid < 2560) { W = oW2; K = 128; N = 128; rowOff = 0;   base = tid - 512; }
  else if (tid < 4608) { W = sW1; K = 128; N = 128; rowOff = 384; base = tid - 2560; }
  else                 { W = sW2; K = 128; N = 64;  rowOff = 0;   base = tid - 4608; }
  int lane = base & 63;
  int fs = base >> 6;
  int NS = K >> 5;
  int s = fs % NS;
  int tt = fs / NS;
  int k = s * 32 + ((lane >> 4) << 3);
  int n = tt * 16 + (lane & 15);
  _Float16* d = dst + (long)tid * 8;
#pragma unroll
  for (int j = 0; j < 8; ++j) d[j] = (_Float16)W[(long)(rowOff + k + j) * N + n];
}

// ---------------- fused GIN layer v2: gather (16 waves) + MFMA MLP (4 waves) ----------------
// 1024 threads = 16 waves; block owns 64 rows. Gather phase: wave w fills Abuf rows
// [w*4, w*4+4) with one-wave-per-node parallelism (4 loads in flight). Barrier. GEMM
// phase: waves 0..3 run GEMM1 -> wave-local hidden in Abuf -> GEMM2 -> z2 + BN stats.
// 2 blocks/CU (thread-capped): co-resident block's gather waves overlap this GEMM phase.
template <bool BN>
__global__ void __launch_bounds__(1024)
fused_gin2(const _Float16* __restrict__ Hprev, const int* __restrict__ rowptr,
           const int* __restrict__ col, const float* __restrict__ accum,
           const float* __restrict__ gamma, const float* __restrict__ beta,
           const _Float16* __restrict__ Wp,
           const float* __restrict__ b1, const float* __restrict__ b2,
           _Float16* __restrict__ Z2, float* __restrict__ accum2) {
  __shared__ _Float16 Abuf[64 * 136];
  __shared__ float red[256];
  const int t = threadIdx.x;
  const int row0 = blockIdx.x * 64;
  const int lane = t & 63;
  const int w = t >> 6;            // 0..15
  const int l15 = lane & 15;
  const int kgrp = lane >> 4;

  // ---- gather phase: wave w fills rows w*4 .. w*4+3 ----
  {
    const int c2 = lane * 2;
    float scx = 1.f, scy = 1.f, shx = 0.f, shy = 0.f;
    if (BN) {
      const float n = (float)NN;
      float mu0 = accum[c2] / n, mu1 = accum[c2 + 1] / n;
      float v0 = accum[128 + c2] / n - mu0 * mu0;
      float v1 = accum[128 + c2 + 1] / n - mu1 * mu1;
      scx = rsqrtf(v0 + 1e-5f) * gamma[c2];
      scy = rsqrtf(v1 + 1e-5f) * gamma[c2 + 1];
      shx = beta[c2] - mu0 * scx;
      shy = beta[c2 + 1] - mu1 * scy;
    }
    auto ldh = [&](int n) -> float2 {
      f16x2 h = *reinterpret_cast<const f16x2*>(Hprev + (long)n * HD + c2);
      float2 v = make_float2((float)h[0], (float)h[1]);
      if (BN) {
        v.x = fmaxf(fmaf(v.x, scx, shx), 0.f);  // BN layers always ReLU'd (i < nl-1)
        v.y = fmaxf(fmaf(v.y, scy, shy), 0.f);
      }
      return v;
    };
#pragma unroll
    for (int i = 0; i < 4; ++i) {
      const int r = w * 4 + i;
      const int node = row0 + r;
      float ax = 0.f, ay = 0.f;
      if (node < NN) {
        const int lo = (node == 0) ? 0 : rowptr[node - 1];
        const int hi = rowptr[node];
        float2 a = ldh(node);
        ax = a.x; ay = a.y;
        int j = lo;
        for (; j + 4 <= hi; j += 4) {
          int s0 = col[j], s1 = col[j + 1], s2 = col[j + 2], s3 = col[j + 3];
          float2 v0 = ldh(s0), v1 = ldh(s1), v2 = ldh(s2), v3 = ldh(s3);
          ax += (v0.x + v1.x) + (v2.x + v3.x);
          ay += (v0.y + v1.y) + (v2.y + v3.y);
        }
        if (j < hi) {
          int last = hi - 1;
          int s0 = col[j];
          int s1 = col[min(j + 1, last)];
          int s2 = col[min(j + 2, last)];
          int s3 = col[min(j + 3, last)];
          float m1 = (j + 1 < hi) ? 1.f : 0.f;
          float m2 = (j + 2 < hi) ? 1.f : 0.f;
          float m3 = (j + 3 < hi) ? 1.f : 0.f;
          float2 v0 = ldh(s0), v1 = ldh(s1), v2 = ldh(s2), v3 = ldh(s3);
          ax += v0.x + m1 * v1.x + m2 * v2.x + m3 * v3.x;
          ay += v0.y + m1 * v1.y + m2 * v2.y + m3 * v3.y;
        }
      }
      f16x2 o;
      o[0] = (_Float16)ax;
      o[1] = (_Float16)ay;
      *reinterpret_cast<f16x2*>(&Abuf[r * 136 + c2]) = o;
    }
  }
  if (t < 256) red[t] = 0.f;
  __syncthreads();

  // ---- GEMM phase: waves 0..3 only (wave w owns rows w*16 .. w*16+16) ----
  if (w < 4) {
    f32x4 acc[8];
    // GEMM1: hidden = ReLU(A @ W1 + b1)
    {
      f16x8 af[4];
#pragma unroll
      for (int s = 0; s < 4; ++s)
        af[s] = *reinterpret_cast<const f16x8*>(&Abuf[(w * 16 + l15) * 136 + s * 32 + kgrp * 8]);
      const _Float16* W1p = Wp;
#pragma unroll
      for (int tt = 0; tt < 8; ++tt) {
        float bb = b1[tt * 16 + l15];
        acc[tt] = (f32x4){bb, bb, bb, bb};
#pragma unroll
        for (int s = 0; s < 4; ++s) {
          f16x8 bf = *reinterpret_cast<const f16x8*>(W1p + ((tt * 4 + s) * 64 + lane) * 8);
          acc[tt] = __builtin_amdgcn_mfma_f32_16x16x32_f16(af[s], bf, acc[tt], 0, 0, 0);
        }
      }
    }
    // hidden -> wave's own (dead) Abuf rows; no barrier (DS wave-ordered)
#pragma unroll
    for (int tt = 0; tt < 8; ++tt) {
#pragma unroll
      for (int j = 0; j < 4; ++j) {
        float v = fmaxf(acc[tt][j], 0.f);
        Abuf[(w * 16 + kgrp * 4 + j) * 136 + tt * 16 + l15] = (_Float16)v;
      }
    }
    // GEMM2: z2 = hidden @ W2 + b2
    {
      f16x8 af[4];
#pragma unroll
      for (int s = 0; s < 4; ++s)
        af[s] = *reinterpret_cast<const f16x8*>(&Abuf[(w * 16 + l15) * 136 + s * 32 + kgrp * 8]);
      const _Float16* W2p = Wp + 16384;
#pragma unroll
      for (int tt = 0; tt < 8; ++tt) {
        float bb = b2[tt * 16 + l15];
        acc[tt] = (f32x4){bb, bb, bb, bb};
#pragma unroll
        for (int s = 0; s < 4; ++s) {
          f16x8 bf = *reinterpret_cast<const f16x8*>(W2p + ((tt * 4 + s) * 64 + lane) * 8);
          acc[tt] = __builtin_amdgcn_mfma_f32_16x16x32_f16(af[s], bf, acc[tt], 0, 0, 0);
        }
      }
    }
    // epilogue: store z2 (fp16) + BN stats into red[]
#pragma unroll
    for (int tt = 0; tt < 8; ++tt) {
      int c = tt * 16 + l15;
      float s = 0.f, q = 0.f;
#pragma unroll
      for (int j = 0; j < 4; ++j) {
        int r = row0 + w * 16 + kgrp * 4 + j;
        if (r < NN) {
          float v = acc[tt][j];
          Z2[(long)r * HD + c] = (_Float16)v;
          s += v; q += v * v;
        }
      }
      atomicAdd(&red[c], s);
      atomicAdd(&red[128 + c], q);
    }
  }
  __syncthreads();
  if (t < 256) atomicAdd(&accum2[(blockIdx.x & (NSUB - 1)) * 256 + t], red[t]);
}

// ---------------- reduce sub-accumulators -> accum[256] ----------------
__global__ void bn_reduce(const float* __restrict__ accum2, float* __restrict__ accum) {
  const int c = threadIdx.x;  // 256
  float s = 0.f;
  for (int i = 0; i < NSUB; ++i) s += accum2[i * 256 + c];
  accum[c] = s;
}

// ---------------- 3-phase parallel pooling ----------------
__global__ void pool_init(float* __restrict__ ssum, unsigned int* __restrict__ smaxU) {
  int i = blockIdx.x * 256 + threadIdx.x;  // 32768
  ssum[i] = 0.f;
  smaxU[i] = 0x007FFFFFu;  // enc(-inf)
}

__global__ void pool_partial(const _Float16* __restrict__ z2, const float* __restrict__ accum,
                             const float* __restrict__ gamma, const float* __restrict__ beta,
                             const int* __restrict__ batch,
                             float* __restrict__ ssum, unsigned int* __restrict__ smaxU) {
  const int c = threadIdx.x;  // 128
  const int row0 = blockIdx.x * POOL_ROWS;
  const int rowEnd = min(row0 + POOL_ROWS, NN);
  const float n = (float)NN;
  float mu = accum[c] / n;
  float var = accum[128 + c] / n - mu * mu;
  const float sc = rsqrtf(var + 1e-5f) * gamma[c];
  const float sh = beta[c] - mu * sc;

  int curb = batch[row0];
  float s = 0.f, m = -INFINITY;
  for (int row = row0; row < rowEnd; ++row) {
    int b = batch[row];
    if (b != curb) {
      atomicAdd(&ssum[curb * HD + c], s);
      atomicMax(&smaxU[curb * HD + c], encf(m));
      s = 0.f; m = -INFINITY; curb = b;
    }
    float v = fmaf((float)z2[(long)row * HD + c], sc, sh);
    s += v;
    m = fmaxf(m, v);
  }
  atomicAdd(&ssum[curb * HD + c], s);
  atomicMax(&smaxU[curb * HD + c], encf(m));
}

__global__ void pool_final(const int* __restrict__ batch, float* __restrict__ ssum,
                           unsigned int* __restrict__ smaxU, float* __restrict__ smean,
                           float* __restrict__ smax) {
  const int b = blockIdx.x;   // 256
  const int c = threadIdx.x;  // 128
  int lo = 0, hi = NN;
  while (lo < hi) { int mid = (lo + hi) >> 1; if (batch[mid] < b) lo = mid + 1; else hi = mid; }
  const int start = lo;
  hi = NN;
  while (lo < hi) { int mid = (lo + hi) >> 1; if (batch[mid] < b + 1) lo = mid + 1; else hi = mid; }
  const int cnt = lo - start;
  float s = ssum[b * HD + c];
  smean[b * HD + c] = s / fmaxf((float)cnt, 1.f);
  smax[b * HD + c] = (cnt > 0) ? decf(smaxU[b * HD + c]) : 0.f;
}

// ---------------- gpart[b] = graph[b] @ sW1[0:384] + sb1 ----------------
__global__ void gpart_kernel(const float* __restrict__ smean, const float* __restrict__ smax,
                             const float* __restrict__ ssum, const float* __restrict__ sW1,
                             const float* __restrict__ sb1, float* __restrict__ gpart) {
  const int b = blockIdx.x;   // 256
  const int j = threadIdx.x;  // 128
  float acc = sb1[j];
  for (int k = 0; k < 128; ++k) acc = fmaf(smean[b * HD + k], sW1[k * 128 + j], acc);
  for (int k = 0; k < 128; ++k) acc = fmaf(smax[b * HD + k], sW1[(128 + k) * 128 + j], acc);
  for (int k = 0; k < 128; ++k) acc = fmaf(ssum[b * HD + k], sW1[(256 + k) * 128 + j], acc);
  gpart[b * HD + j] = acc;
}

// ---------------- head MFMA: per-order chain, one block per graph ----------------
__global__ void __launch_bounds__(128)
head_mfma(const float* __restrict__ orders, const _Float16* __restrict__ Wh,
          const float* __restrict__ ob1, const float* __restrict__ ob2,
          const float* __restrict__ gpart, const float* __restrict__ sb2,
          const float* __restrict__ sW3, const float* __restrict__ sb3,
          float* __restrict__ out) {
  __shared__ _Float16 B1[32 * 136];
  __shared__ _Float16 B2[32 * 136];
  const int t = threadIdx.x;
  const int g = blockIdx.x;
  const int row0 = g * 32;
  const int lane = t & 63;
  const int w = t >> 6;
  const int l15 = lane & 15;
  const int kgrp = lane >> 4;
  const _Float16* oW1p  = Wh;
  const _Float16* oW2p  = Wh + 4096;
  const _Float16* sW1bp = Wh + 20480;
  const _Float16* sW2p  = Wh + 36864;

  for (int idx = t; idx < 32 * 8; idx += 128) {
    int r = idx >> 3;
    int c4 = (idx & 7) * 4;
    float4 v = *reinterpret_cast<const float4*>(orders + (long)(row0 + r) * 32 + c4);
    f16x4 h;
    h[0] = (_Float16)v.x; h[1] = (_Float16)v.y; h[2] = (_Float16)v.z; h[3] = (_Float16)v.w;
    *reinterpret_cast<f16x4*>(&B1[r * 136 + c4]) = h;
  }
  __syncthreads();

  f32x4 acc[8];
  {
    f16x8 a0 = *reinterpret_cast<const f16x8*>(&B1[(w * 16 + l15) * 136 + kgrp * 8]);
#pragma unroll
    for (int tt = 0; tt < 8; ++tt) {
      float bb = ob1[tt * 16 + l15];
      acc[tt] = (f32x4){bb, bb, bb, bb};
      f16x8 bf = *reinterpret_cast<const f16x8*>(oW1p + (tt * 64 + lane) * 8);
      acc[tt] = __builtin_amdgcn_mfma_f32_16x16x32_f16(a0, bf, acc[tt], 0, 0, 0);
    }
#pragma unroll
    for (int tt = 0; tt < 8; ++tt)
#pragma unroll
      for (int j = 0; j < 4; ++j)
        B2[(w * 16 + kgrp * 4 + j) * 136 + tt * 16 + l15] = (_Float16)fmaxf(acc[tt][j], 0.f);
  }
  {
    f16x8 af[4];
#pragma unroll
    for (int s = 0; s < 4; ++s)
      af[s] = *reinterpret_cast<const f16x8*>(&B2[(w * 16 + l15) * 136 + s * 32 + kgrp * 8]);
#pragma unroll
    for (int tt = 0; tt < 8; ++tt) {
      float bb = ob2[tt * 16 + l15];
      acc[tt] = (f32x4){bb, bb, bb, bb};
#pragma unroll
      for (int s = 0; s < 4; ++s) {
        f16x8 bf = *reinterpret_cast<const f16x8*>(oW2p + ((tt * 4 + s) * 64 + lane) * 8);
        acc[tt] = __builtin_amdgcn_mfma_f32_16x16x32_f16(af[s], bf, acc[tt], 0, 0, 0);
      }
    }
#pragma unroll
    for (int tt = 0; tt < 8; ++tt)
#pragma unroll
      for (int j = 0; j < 4; ++j)
        B1[(w * 16 + kgrp * 4 + j) * 136 + tt * 16 + l15] = (_Float16)acc[tt][j];
  }
  {
    f16x8 af[4];
#pragma unroll
    for (int s = 0; s < 4; ++s)
      af[s] = *reinterpret_cast<const f16x8*>(&B1[(w * 16 + l15) * 136 + s * 32 + kgrp * 8]);
#pragma unroll
    for (int tt = 0; tt < 8; ++tt) {
      acc[tt] = (f32x4){0.f, 0.f, 0.f, 0.f};
#pragma unroll
      for (int s = 0; s < 4; ++s) {
        f16x8 bf = *reinterpret_cast<const f16x8*>(sW1bp + ((tt * 4 + s) * 64 + lane) * 8);
        acc[tt] = __builtin_amdgcn_mfma_f32_16x16x32_f16(af[s], bf, acc[tt], 0, 0, 0);
      }
    }
#pragma unroll
    for (int tt = 0; tt < 8; ++tt) {
      int c = tt * 16 + l15;
      float gp = gpart[g * HD + c];
#pragma unroll
      for (int j = 0; j < 4; ++j)
        B2[(w * 16 + kgrp * 4 + j) * 136 + c] = (_Float16)fmaxf(acc[tt][j] + gp, 0.f);
    }
  }
  {
    f16x8 af[4];
#pragma unroll
    for (int s = 0; s < 4; ++s)
      af[s] = *reinterpret_cast<const f16x8*>(&B2[(w * 16 + l15) * 136 + s * 32 + kgrp * 8]);
#pragma unroll
    for (int tt = 0; tt < 4; ++tt) {
      float bb = sb2[tt * 16 + l15];
      acc[tt] = (f32x4){bb, bb, bb, bb};
#pragma unroll
      for (int s = 0; s < 4; ++s) {
        f16x8 bf = *reinterpret_cast<const f16x8*>(sW2p + ((tt * 4 + s) * 64 + lane) * 8);
        acc[tt] = __builtin_amdgcn_mfma_f32_16x16x32_f16(af[s], bf, acc[tt], 0, 0, 0);
      }
    }
    float rsum[4] = {0.f, 0.f, 0.f, 0.f};
#pragma unroll
    for (int tt = 0; tt < 4; ++tt) {
      float wv = sW3[tt * 16 + l15];
#pragma unroll
      for (int j = 0; j < 4; ++j)
        rsum[j] = fmaf(fmaxf(acc[tt][j], 0.f), wv, rsum[j]);
    }
#pragma unroll
    for (int j = 0; j < 4; ++j) {
      rsum[j] += __shfl_xor(rsum[j], 1);
      rsum[j] += __shfl_xor(rsum[j], 2);
      rsum[j] += __shfl_xor(rsum[j], 4);
      rsum[j] += __shfl_xor(rsum[j], 8);
    }
    if (l15 == 0) {
      float b3 = sb3[0];
#pragma unroll
      for (int j = 0; j < 4; ++j)
        out[row0 + w * 16 + kgrp * 4 + j] = rsum[j] + b3;
    }
  }
}

extern "C" void kernel_launch(void* const* d_in, const int* in_sizes, int n_in,
                              void* d_out, int out_size, void* d_ws, size_t ws_size,
                              hipStream_t stream) {
  const float* x      = (const float*)d_in[0];
  const int*   ei     = (const int*)d_in[1];
  const float* orders = (const float*)d_in[2];
  const int*   batch  = (const int*)d_in[3];
  const float* gW1    = (const float*)d_in[4];
  const float* gb1    = (const float*)d_in[5];
  const float* gW2    = (const float*)d_in[6];
  const float* gb2    = (const float*)d_in[7];
  const float* gamma  = (const float*)d_in[8];
  const float* beta   = (const float*)d_in[9];
  const float* oW1    = (const float*)d_in[10];
  const float* ob1    = (const float*)d_in[11];
  const float* oW2    = (const float*)d_in[12];
  const float* ob2    = (const float*)d_in[13];
  const float* sW1    = (const float*)d_in[14];
  const float* sb1    = (const float*)d_in[15];
  const float* sW2    = (const float*)d_in[16];
  const float* sb2    = (const float*)d_in[17];
  const float* sW3    = (const float*)d_in[18];
  const float* sb3    = (const float*)d_in[19];
  float* out = (float*)d_out;

  char* ws = (char*)d_ws;
  _Float16* xh    = (_Float16*)ws;                // x fp16        [NN,128]
  _Float16* bufAh = xh + NH;                      // z2 ping       [NN,128]
  _Float16* bufCh = bufAh + NH;                   // z2 pong       [NN,128]
  float* accum  = (float*)(bufCh + NH);           // 256 (reduced stats)
  float* accum2 = accum + 256;                    // NSUB*256 sub-accumulators
  float* ssum   = accum2 + NSUB * 256;            // 256*128
  float* smean  = ssum + NB * HD;                 // 256*128
  float* smax   = smean + NB * HD;                // 256*128
  unsigned int* smaxU = (unsigned int*)(smax + NB * HD);  // 256*128
  float* gpart = (float*)(smaxU + NB * HD);       // 256*128
  int* rowptr = (int*)(gpart + NB * HD);          // NN
  int* col    = rowptr + NN;                      // NE
  unsigned int* binned = (unsigned int*)(col + NE);  // NE
  int* bucketTotal = (int*)(binned + NE);         // 256
  int* bucketBase  = bucketTotal + NBUCK;         // 257
  int* cursor      = bucketBase + NBUCK + 1;      // 256
  _Float16* Wp  = (_Float16*)(cursor + NBUCK);    // 3*2*16384 fp16 (GIN)
  _Float16* Wh  = Wp + 3 * 32768;                 // 45056 fp16 (head)

  // ---- CSR build (by dst): two-level locality-aware counting sort ----
  hipMemsetAsync(bucketTotal, 0, NBUCK * sizeof(int), stream);
  bucket_count<<<NCHUNK, 256, 0, stream>>>(ei, bucketTotal);
  bucket_scan<<<1, NBUCK, 0, stream>>>(bucketTotal, bucketBase, cursor);
  bucket_scatter<<<NCHUNK, 256, 0, stream>>>(ei, cursor, binned);
  bucket_csr<<<NBUCK, 256, 0, stream>>>(binned, bucketBase, rowptr, col);

  // ---- pack weights + convert x, once ----
  pack_w_kernel<<<48, 256, 0, stream>>>(gW1, gW2, Wp);
  pack_head_kernel<<<22, 256, 0, stream>>>(oW1, oW2, sW1, sW2, Wh);
  f32to16_kernel<<<(int)(NH / 8 + 255) / 256, 256, 0, stream>>>(x, xh);

  const int LAYER_GRID = (NN + 63) / 64;  // 1563
  // layer 0: xh -> bufCh ; layer 1: bufCh -> bufAh ; layer 2: bufAh -> bufCh
  const _Float16* srcs[3] = {xh, bufCh, bufAh};
  _Float16* dsts[3] = {bufCh, bufAh, bufCh};
  for (int l = 0; l < 3; ++l) {
    hipMemsetAsync(accum2, 0, NSUB * 256 * sizeof(float), stream);
    if (l == 0)
      fused_gin2<false><<<LAYER_GRID, 1024, 0, stream>>>(
          srcs[l], rowptr, col, accum, gamma, beta, Wp, gb1, gb2, dsts[l], accum2);
    else
      fused_gin2<true><<<LAYER_GRID, 1024, 0, stream>>>(
          srcs[l], rowptr, col, accum, gamma + (l - 1) * 128, beta + (l - 1) * 128,
          Wp + (long)l * 32768, gb1 + l * 128, gb2 + l * 128, dsts[l], accum2);
    bn_reduce<<<1, 256, 0, stream>>>(accum2, accum);
  }

  // ---- 3-phase pooling (BN of last layer fused into partial) ----
  pool_init<<<128, 256, 0, stream>>>(ssum, smaxU);
  pool_partial<<<POOL_GRID, 128, 0, stream>>>(bufCh, accum, gamma + 2 * 128, beta + 2 * 128,
                                              batch, ssum, smaxU);
  pool_final<<<NB, 128, 0, stream>>>(batch, ssum, smaxU, smean, smax);

  // ---- head: hoisted graph part + per-order MFMA chain ----
  gpart_kernel<<<NB, 128, 0, stream>>>(smean, smax, ssum, sW1, sb1, gpart);
  head_mfma<<<NB, 128, 0, stream>>>(orders, Wh, ob1, ob2, gpart, sb2, sW3, sb3, out);
}

// Round 13
// 548.342 us; speedup vs baseline: 1.5056x; 1.5056x over previous
//
#include <hip/hip_runtime.h>

static constexpr int NN = 100000;   // nodes
static constexpr int NE = 1600000;  // edges
static constexpr int NB = 256;     // graphs
static constexpr int NO = 32;      // orders per graph
static constexpr int HD = 128;     // hidden dim
static constexpr long NH = (long)NN * HD;

static constexpr int BSHIFT = 9;                 // bucket = dst >> 9
static constexpr int BSIZE = 1 << BSHIFT;        // 512 nodes per bucket
static constexpr int NBUCK = 256;
static constexpr int CHUNK = 16384;
static constexpr int NCHUNK = (NE + CHUNK - 1) / CHUNK;  // 98
static constexpr int POOL_ROWS = 64;
static constexpr int POOL_GRID = (NN + POOL_ROWS - 1) / POOL_ROWS;  // 1563
static constexpr int NSUB = 64;                  // BN stat sub-accumulators
static constexpr int GATHER_GRID = NN / 4;       // 25000 (divisible by 8)

typedef _Float16 f16x8 __attribute__((ext_vector_type(8)));
typedef _Float16 f16x4 __attribute__((ext_vector_type(4)));
typedef _Float16 f16x2 __attribute__((ext_vector_type(2)));
typedef float f32x4 __attribute__((ext_vector_type(4)));

__device__ __forceinline__ unsigned int encf(float f) {
  unsigned int u = __float_as_uint(f);
  return (u & 0x80000000u) ? ~u : (u | 0x80000000u);
}
__device__ __forceinline__ float decf(unsigned int e) {
  return (e & 0x80000000u) ? __uint_as_float(e & 0x7fffffffu) : __uint_as_float(~e);
}

// ================= CSR build: two-level locality-aware counting sort =================
__global__ void bucket_count(const int* __restrict__ ei, int* __restrict__ bucketTotal) {
  __shared__ int cnt[NBUCK];
  const int t = threadIdx.x;  // 256
  cnt[t] = 0;
  __syncthreads();
  long start = (long)blockIdx.x * CHUNK;
  long end = min((long)NE, start + CHUNK);
  for (long e = start + t; e < end; e += 256)
    atomicAdd(&cnt[ei[NE + e] >> BSHIFT], 1);
  __syncthreads();
  if (cnt[t]) atomicAdd(&bucketTotal[t], cnt[t]);
}

__global__ void bucket_scan(const int* __restrict__ bucketTotal, int* __restrict__ bucketBase,
                            int* __restrict__ cursor) {
  __shared__ int part[NBUCK];
  const int t = threadIdx.x;  // 256
  int v = bucketTotal[t];
  part[t] = v;
  __syncthreads();
  for (int off = 1; off < NBUCK; off <<= 1) {
    int u = (t >= off) ? part[t - off] : 0;
    __syncthreads();
    part[t] += u;
    __syncthreads();
  }
  int base = part[t] - v;
  bucketBase[t] = base;
  cursor[t] = base;
  if (t == NBUCK - 1) bucketBase[NBUCK] = part[t];
}

__global__ void bucket_scatter(const int* __restrict__ ei, int* __restrict__ cursor,
                               unsigned int* __restrict__ binned) {
  __shared__ int cnt[NBUCK];
  __shared__ int runbase[NBUCK];
  const int t = threadIdx.x;  // 256
  cnt[t] = 0;
  __syncthreads();
  long start = (long)blockIdx.x * CHUNK;
  long end = min((long)NE, start + CHUNK);
  for (long e = start + t; e < end; e += 256)
    atomicAdd(&cnt[ei[NE + e] >> BSHIFT], 1);
  __syncthreads();
  int c = cnt[t];
  runbase[t] = c ? atomicAdd(&cursor[t], c) : 0;
  cnt[t] = 0;  // reuse as local run cursor
  __syncthreads();
  for (long e = start + t; e < end; e += 256) {
    int d = ei[NE + e], s = ei[e];
    int b = d >> BSHIFT;
    int pos = runbase[b] + atomicAdd(&cnt[b], 1);
    binned[pos] = ((unsigned int)s << BSHIFT) | (unsigned int)(d & (BSIZE - 1));
  }
}

__global__ void bucket_csr(const unsigned int* __restrict__ binned,
                           const int* __restrict__ bucketBase,
                           int* __restrict__ rowptr, int* __restrict__ col) {
  __shared__ int cnt[BSIZE];
  __shared__ int excl[BSIZE];
  __shared__ int cur[BSIZE];
  __shared__ int part[256];
  const int b = blockIdx.x;
  const int t = threadIdx.x;  // 256
  const int lo = bucketBase[b], hi = bucketBase[b + 1];
  cnt[t] = 0; cnt[t + 256] = 0;
  __syncthreads();
  for (int i = lo + t; i < hi; i += 256)
    atomicAdd(&cnt[binned[i] & (BSIZE - 1)], 1);
  __syncthreads();
  int a0 = cnt[2 * t], a1 = cnt[2 * t + 1];
  int s = a0 + a1;
  part[t] = s;
  __syncthreads();
  for (int off = 1; off < 256; off <<= 1) {
    int u = (t >= off) ? part[t - off] : 0;
    __syncthreads();
    part[t] += u;
    __syncthreads();
  }
  int ebase = part[t] - s;
  excl[2 * t] = ebase;
  excl[2 * t + 1] = ebase + a0;
  __syncthreads();
  const int node0 = b * BSIZE;
  for (int i = t; i < BSIZE; i += 256) {
    int node = node0 + i;
    if (node < NN) rowptr[node] = lo + excl[i] + cnt[i];  // inclusive end
    cur[i] = lo + excl[i];
  }
  __syncthreads();
  for (int i = lo + t; i < hi; i += 256) {
    unsigned int v = binned[i];
    int pos = atomicAdd(&cur[v & (BSIZE - 1)], 1);
    col[pos] = (int)(v >> BSHIFT);
  }
}

// ---------------- x fp32 -> fp16, once ----------------
__global__ void f32to16_kernel(const float* __restrict__ in, _Float16* __restrict__ out) {
  long i = (long)(blockIdx.x * 256 + threadIdx.x) * 8;
  if (i >= NH) return;
  float4 a = *reinterpret_cast<const float4*>(in + i);
  float4 b = *reinterpret_cast<const float4*>(in + i + 4);
  f16x8 v;
  v[0] = (_Float16)a.x; v[1] = (_Float16)a.y; v[2] = (_Float16)a.z; v[3] = (_Float16)a.w;
  v[4] = (_Float16)b.x; v[5] = (_Float16)b.y; v[6] = (_Float16)b.z; v[7] = (_Float16)b.w;
  *reinterpret_cast<f16x8*>(out + i) = v;
}

// ---------------- weight packing: fp32 W[128][128] -> fp16 MFMA B-fragments (GIN) ----------------
__global__ void pack_w_kernel(const float* __restrict__ gW1, const float* __restrict__ gW2,
                              _Float16* __restrict__ Wp) {
  int tid = blockIdx.x * blockDim.x + threadIdx.x;  // 3*2*8*4*64 = 12288
  if (tid >= 12288) return;
  int lane = tid & 63;
  int s = (tid >> 6) & 3;
  int t = (tid >> 8) & 7;
  int which = (tid >> 11) & 1;
  int layer = tid >> 12;
  const float* W = (which ? gW2 : gW1) + (long)layer * 128 * 128;
  _Float16* dst = Wp + (long)tid * 8;
  int kbase = s * 32 + ((lane >> 4) << 3);
  int n = t * 16 + (lane & 15);
#pragma unroll
  for (int j = 0; j < 8; ++j) dst[j] = (_Float16)W[(kbase + j) * 128 + n];
}

// ---------------- head weight packing ----------------
__global__ void pack_head_kernel(const float* __restrict__ oW1, const float* __restrict__ oW2,
                                 const float* __restrict__ sW1, const float* __restrict__ sW2,
                                 _Float16* __restrict__ dst) {
  int tid = blockIdx.x * blockDim.x + threadIdx.x;  // 5632 total
  if (tid >= 5632) return;
  const float* W; int K, N, rowOff;
  int base = tid;
  if (tid < 512)       { W = oW1; K = 32;  N = 128; rowOff = 0;   }
  else if (tid < 2560) { W = oW2; K = 128; N = 128; rowOff = 0;   base = tid - 512; }
  else if (tid < 4608) { W = sW1; K = 128; N = 128; rowOff = 384; base = tid - 2560; }
  else                 { W = sW2; K = 128; N = 64;  rowOff = 0;   base = tid - 4608; }
  int lane = base & 63;
  int fs = base >> 6;
  int NS = K >> 5;
  int s = fs % NS;
  int tt = fs / NS;
  int k = s * 32 + ((lane >> 4) << 3);
  int n = tt * 16 + (lane & 15);
  _Float16* d = dst + (long)tid * 8;
#pragma unroll
  for (int j = 0; j < 8; ++j) d[j] = (_Float16)W[(long)(rowOff + k + j) * N + n];
}

// ---------------- gather: z[n] = f(hin[n]) + sum_j f(hin[col[j]]) ----------------
// one wave per node; XCD-aware bijective block swizzle: each XCD walks a contiguous
// node range, so co-resident blocks share a sliding row-window that fits its L2.
template <bool BN, bool RELU>
__global__ void gather_kernel(const _Float16* __restrict__ hin, const int* __restrict__ rowptr,
                              const int* __restrict__ col, const float* __restrict__ accum,
                              const float* __restrict__ gamma, const float* __restrict__ beta,
                              _Float16* __restrict__ z) {
  const int blk = (blockIdx.x & 7) * (GATHER_GRID / 8) + (blockIdx.x >> 3);  // bijective
  const int node = blk * 4 + (threadIdx.x >> 6);
  if (node >= NN) return;
  const int c2 = (threadIdx.x & 63) * 2;
  float scx = 1.f, scy = 1.f, shx = 0.f, shy = 0.f;
  if (BN) {
    const float n = (float)NN;
    float mu0 = accum[c2] / n, mu1 = accum[c2 + 1] / n;
    float v0 = accum[128 + c2] / n - mu0 * mu0;
    float v1 = accum[128 + c2 + 1] / n - mu1 * mu1;
    scx = rsqrtf(v0 + 1e-5f) * gamma[c2];
    scy = rsqrtf(v1 + 1e-5f) * gamma[c2 + 1];
    shx = beta[c2] - mu0 * scx;
    shy = beta[c2 + 1] - mu1 * scy;
  }
  auto ldh = [&](int n) -> float2 {
    f16x2 h = *reinterpret_cast<const f16x2*>(hin + (long)n * HD + c2);
    float2 v = make_float2((float)h[0], (float)h[1]);
    if (BN) {
      v.x = fmaf(v.x, scx, shx);
      v.y = fmaf(v.y, scy, shy);
      if (RELU) { v.x = fmaxf(v.x, 0.f); v.y = fmaxf(v.y, 0.f); }
    }
    return v;
  };
  const int lo = (node == 0) ? 0 : rowptr[node - 1];
  const int hi = rowptr[node];
  float2 acc = ldh(node);
  int j = lo;
  for (; j + 4 <= hi; j += 4) {
    int s0 = col[j], s1 = col[j + 1], s2 = col[j + 2], s3 = col[j + 3];
    float2 v0 = ldh(s0), v1 = ldh(s1), v2 = ldh(s2), v3 = ldh(s3);
    acc.x += (v0.x + v1.x) + (v2.x + v3.x);
    acc.y += (v0.y + v1.y) + (v2.y + v3.y);
  }
  if (j < hi) {
    int last = hi - 1;
    int s0 = col[j];
    int s1 = col[min(j + 1, last)];
    int s2 = col[min(j + 2, last)];
    int s3 = col[min(j + 3, last)];
    float m1 = (j + 1 < hi) ? 1.f : 0.f;
    float m2 = (j + 2 < hi) ? 1.f : 0.f;
    float m3 = (j + 3 < hi) ? 1.f : 0.f;
    float2 v0 = ldh(s0), v1 = ldh(s1), v2 = ldh(s2), v3 = ldh(s3);
    acc.x += v0.x + m1 * v1.x + m2 * v2.x + m3 * v3.x;
    acc.y += v0.y + m1 * v1.y + m2 * v2.y + m3 * v3.y;
  }
  f16x2 o;
  o[0] = (_Float16)acc.x;
  o[1] = (_Float16)acc.y;
  *reinterpret_cast<f16x2*>(z + (long)node * HD + c2) = o;
}

// ---------------- fused GIN MLP: z2 = (ReLU(z@W1+b1))@W2 + b2, BN stats fused ----------------
// 64 rows/block, 4 waves. Single LDS buffer: hidden overwrites the wave's own dead Abuf
// rows (DS ops are wave-ordered). 18.4KB LDS -> 8 blocks/CU. Stats go to hierarchical accum2.
__global__ void __launch_bounds__(256)
fused_layer(const _Float16* __restrict__ Z, const _Float16* __restrict__ Wp,
            const float* __restrict__ b1, const float* __restrict__ b2,
            _Float16* __restrict__ Z2, float* __restrict__ accum2) {
  __shared__ _Float16 Abuf[64 * 136];
  __shared__ float red[256];
  const int t = threadIdx.x;
  const int row0 = blockIdx.x * 64;
  const int lane = t & 63;
  const int w = t >> 6;
  const int l15 = lane & 15;
  const int kgrp = lane >> 4;

  for (int idx = t; idx < 64 * 16; idx += 256) {
    int r = idx >> 4;
    int c8 = (idx & 15) * 8;
    int row = row0 + r;
    f16x8 v = {};
    if (row < NN) v = *reinterpret_cast<const f16x8*>(Z + (long)row * HD + c8);
    *reinterpret_cast<f16x8*>(&Abuf[r * 136 + c8]) = v;
  }
  red[t] = 0.f;
  __syncthreads();

  f32x4 acc[8];
  // ---- GEMM1: hidden = ReLU(A @ W1 + b1) ---- (wave-local rows)
  {
    f16x8 af[4];
#pragma unroll
    for (int s = 0; s < 4; ++s)
      af[s] = *reinterpret_cast<const f16x8*>(&Abuf[(w * 16 + l15) * 136 + s * 32 + kgrp * 8]);
    const _Float16* W1p = Wp;
#pragma unroll
    for (int tt = 0; tt < 8; ++tt) {
      float bb = b1[tt * 16 + l15];
      acc[tt] = (f32x4){bb, bb, bb, bb};
#pragma unroll
      for (int s = 0; s < 4; ++s) {
        f16x8 bf = *reinterpret_cast<const f16x8*>(W1p + ((tt * 4 + s) * 64 + lane) * 8);
        acc[tt] = __builtin_amdgcn_mfma_f32_16x16x32_f16(af[s], bf, acc[tt], 0, 0, 0);
      }
    }
  }
  // hidden -> wave's own (now dead) Abuf rows; no barrier (DS wave-ordered)
#pragma unroll
  for (int tt = 0; tt < 8; ++tt) {
#pragma unroll
    for (int j = 0; j < 4; ++j) {
      float v = fmaxf(acc[tt][j], 0.f);
      Abuf[(w * 16 + kgrp * 4 + j) * 136 + tt * 16 + l15] = (_Float16)v;
    }
  }
  // ---- GEMM2: z2 = hidden @ W2 + b2 ----
  {
    f16x8 af[4];
#pragma unroll
    for (int s = 0; s < 4; ++s)
      af[s] = *reinterpret_cast<const f16x8*>(&Abuf[(w * 16 + l15) * 136 + s * 32 + kgrp * 8]);
    const _Float16* W2p = Wp + 16384;
#pragma unroll
    for (int tt = 0; tt < 8; ++tt) {
      float bb = b2[tt * 16 + l15];
      acc[tt] = (f32x4){bb, bb, bb, bb};
#pragma unroll
      for (int s = 0; s < 4; ++s) {
        f16x8 bf = *reinterpret_cast<const f16x8*>(W2p + ((tt * 4 + s) * 64 + lane) * 8);
        acc[tt] = __builtin_amdgcn_mfma_f32_16x16x32_f16(af[s], bf, acc[tt], 0, 0, 0);
      }
    }
  }
  // ---- epilogue: store z2 (fp16) + BN stats ----
#pragma unroll
  for (int tt = 0; tt < 8; ++tt) {
    int c = tt * 16 + l15;
    float s = 0.f, q = 0.f;
#pragma unroll
    for (int j = 0; j < 4; ++j) {
      int r = row0 + w * 16 + kgrp * 4 + j;
      if (r < NN) {
        float v = acc[tt][j];
        Z2[(long)r * HD + c] = (_Float16)v;
        s += v; q += v * v;
      }
    }
    atomicAdd(&red[c], s);
    atomicAdd(&red[128 + c], q);
  }
  __syncthreads();
  atomicAdd(&accum2[(blockIdx.x & (NSUB - 1)) * 256 + t], red[t]);
}

// ---------------- reduce sub-accumulators -> accum[256] ----------------
__global__ void bn_reduce(const float* __restrict__ accum2, float* __restrict__ accum) {
  const int c = threadIdx.x;  // 256
  float s = 0.f;
  for (int i = 0; i < NSUB; ++i) s += accum2[i * 256 + c];
  accum[c] = s;
}

// ---------------- 3-phase parallel pooling ----------------
__global__ void pool_init(float* __restrict__ ssum, unsigned int* __restrict__ smaxU) {
  int i = blockIdx.x * 256 + threadIdx.x;  // 32768
  ssum[i] = 0.f;
  smaxU[i] = 0x007FFFFFu;  // enc(-inf)
}

__global__ void pool_partial(const _Float16* __restrict__ z2, const float* __restrict__ accum,
                             const float* __restrict__ gamma, const float* __restrict__ beta,
                             const int* __restrict__ batch,
                             float* __restrict__ ssum, unsigned int* __restrict__ smaxU) {
  const int c = threadIdx.x;  // 128
  const int row0 = blockIdx.x * POOL_ROWS;
  const int rowEnd = min(row0 + POOL_ROWS, NN);
  const float n = (float)NN;
  float mu = accum[c] / n;
  float var = accum[128 + c] / n - mu * mu;
  const float sc = rsqrtf(var + 1e-5f) * gamma[c];
  const float sh = beta[c] - mu * sc;

  int curb = batch[row0];
  float s = 0.f, m = -INFINITY;
  for (int row = row0; row < rowEnd; ++row) {
    int b = batch[row];
    if (b != curb) {
      atomicAdd(&ssum[curb * HD + c], s);
      atomicMax(&smaxU[curb * HD + c], encf(m));
      s = 0.f; m = -INFINITY; curb = b;
    }
    float v = fmaf((float)z2[(long)row * HD + c], sc, sh);
    s += v;
    m = fmaxf(m, v);
  }
  atomicAdd(&ssum[curb * HD + c], s);
  atomicMax(&smaxU[curb * HD + c], encf(m));
}

__global__ void pool_final(const int* __restrict__ batch, float* __restrict__ ssum,
                           unsigned int* __restrict__ smaxU, float* __restrict__ smean,
                           float* __restrict__ smax) {
  const int b = blockIdx.x;   // 256
  const int c = threadIdx.x;  // 128
  int lo = 0, hi = NN;
  while (lo < hi) { int mid = (lo + hi) >> 1; if (batch[mid] < b) lo = mid + 1; else hi = mid; }
  const int start = lo;
  hi = NN;
  while (lo < hi) { int mid = (lo + hi) >> 1; if (batch[mid] < b + 1) lo = mid + 1; else hi = mid; }
  const int cnt = lo - start;
  float s = ssum[b * HD + c];
  smean[b * HD + c] = s / fmaxf((float)cnt, 1.f);
  smax[b * HD + c] = (cnt > 0) ? decf(smaxU[b * HD + c]) : 0.f;
}

// ---------------- gpart[b] = graph[b] @ sW1[0:384] + sb1 ----------------
__global__ void gpart_kernel(const float* __restrict__ smean, const float* __restrict__ smax,
                             const float* __restrict__ ssum, const float* __restrict__ sW1,
                             const float* __restrict__ sb1, float* __restrict__ gpart) {
  const int b = blockIdx.x;   // 256
  const int j = threadIdx.x;  // 128
  float acc = sb1[j];
  for (int k = 0; k < 128; ++k) acc = fmaf(smean[b * HD + k], sW1[k * 128 + j], acc);
  for (int k = 0; k < 128; ++k) acc = fmaf(smax[b * HD + k], sW1[(128 + k) * 128 + j], acc);
  for (int k = 0; k < 128; ++k) acc = fmaf(ssum[b * HD + k], sW1[(256 + k) * 128 + j], acc);
  gpart[b * HD + j] = acc;
}

// ---------------- head MFMA: per-order chain, one block per graph ----------------
__global__ void __launch_bounds__(128)
head_mfma(const float* __restrict__ orders, const _Float16* __restrict__ Wh,
          const float* __restrict__ ob1, const float* __restrict__ ob2,
          const float* __restrict__ gpart, const float* __restrict__ sb2,
          const float* __restrict__ sW3, const float* __restrict__ sb3,
          float* __restrict__ out) {
  __shared__ _Float16 B1[32 * 136];
  __shared__ _Float16 B2[32 * 136];
  const int t = threadIdx.x;
  const int g = blockIdx.x;
  const int row0 = g * 32;
  const int lane = t & 63;
  const int w = t >> 6;
  const int l15 = lane & 15;
  const int kgrp = lane >> 4;
  const _Float16* oW1p  = Wh;
  const _Float16* oW2p  = Wh + 4096;
  const _Float16* sW1bp = Wh + 20480;
  const _Float16* sW2p  = Wh + 36864;

  for (int idx = t; idx < 32 * 8; idx += 128) {
    int r = idx >> 3;
    int c4 = (idx & 7) * 4;
    float4 v = *reinterpret_cast<const float4*>(orders + (long)(row0 + r) * 32 + c4);
    f16x4 h;
    h[0] = (_Float16)v.x; h[1] = (_Float16)v.y; h[2] = (_Float16)v.z; h[3] = (_Float16)v.w;
    *reinterpret_cast<f16x4*>(&B1[r * 136 + c4]) = h;
  }
  __syncthreads();

  f32x4 acc[8];
  {
    f16x8 a0 = *reinterpret_cast<const f16x8*>(&B1[(w * 16 + l15) * 136 + kgrp * 8]);
#pragma unroll
    for (int tt = 0; tt < 8; ++tt) {
      float bb = ob1[tt * 16 + l15];
      acc[tt] = (f32x4){bb, bb, bb, bb};
      f16x8 bf = *reinterpret_cast<const f16x8*>(oW1p + (tt * 64 + lane) * 8);
      acc[tt] = __builtin_amdgcn_mfma_f32_16x16x32_f16(a0, bf, acc[tt], 0, 0, 0);
    }
#pragma unroll
    for (int tt = 0; tt < 8; ++tt)
#pragma unroll
      for (int j = 0; j < 4; ++j)
        B2[(w * 16 + kgrp * 4 + j) * 136 + tt * 16 + l15] = (_Float16)fmaxf(acc[tt][j], 0.f);
  }
  {
    f16x8 af[4];
#pragma unroll
    for (int s = 0; s < 4; ++s)
      af[s] = *reinterpret_cast<const f16x8*>(&B2[(w * 16 + l15) * 136 + s * 32 + kgrp * 8]);
#pragma unroll
    for (int tt = 0; tt < 8; ++tt) {
      float bb = ob2[tt * 16 + l15];
      acc[tt] = (f32x4){bb, bb, bb, bb};
#pragma unroll
      for (int s = 0; s < 4; ++s) {
        f16x8 bf = *reinterpret_cast<const f16x8*>(oW2p + ((tt * 4 + s) * 64 + lane) * 8);
        acc[tt] = __builtin_amdgcn_mfma_f32_16x16x32_f16(af[s], bf, acc[tt], 0, 0, 0);
      }
    }
#pragma unroll
    for (int tt = 0; tt < 8; ++tt)
#pragma unroll
      for (int j = 0; j < 4; ++j)
        B1[(w * 16 + kgrp * 4 + j) * 136 + tt * 16 + l15] = (_Float16)acc[tt][j];
  }
  {
    f16x8 af[4];
#pragma unroll
    for (int s = 0; s < 4; ++s)
      af[s] = *reinterpret_cast<const f16x8*>(&B1[(w * 16 + l15) * 136 + s * 32 + kgrp * 8]);
#pragma unroll
    for (int tt = 0; tt < 8; ++tt) {
      acc[tt] = (f32x4){0.f, 0.f, 0.f, 0.f};
#pragma unroll
      for (int s = 0; s < 4; ++s) {
        f16x8 bf = *reinterpret_cast<const f16x8*>(sW1bp + ((tt * 4 + s) * 64 + lane) * 8);
        acc[tt] = __builtin_amdgcn_mfma_f32_16x16x32_f16(af[s], bf, acc[tt], 0, 0, 0);
      }
    }
#pragma unroll
    for (int tt = 0; tt < 8; ++tt) {
      int c = tt * 16 + l15;
      float gp = gpart[g * HD + c];
#pragma unroll
      for (int j = 0; j < 4; ++j)
        B2[(w * 16 + kgrp * 4 + j) * 136 + c] = (_Float16)fmaxf(acc[tt][j] + gp, 0.f);
    }
  }
  {
    f16x8 af[4];
#pragma unroll
    for (int s = 0; s < 4; ++s)
      af[s] = *reinterpret_cast<const f16x8*>(&B2[(w * 16 + l15) * 136 + s * 32 + kgrp * 8]);
#pragma unroll
    for (int tt = 0; tt < 4; ++tt) {
      float bb = sb2[tt * 16 + l15];
      acc[tt] = (f32x4){bb, bb, bb, bb};
#pragma unroll
      for (int s = 0; s < 4; ++s) {
        f16x8 bf = *reinterpret_cast<const f16x8*>(sW2p + ((tt * 4 + s) * 64 + lane) * 8);
        acc[tt] = __builtin_amdgcn_mfma_f32_16x16x32_f16(af[s], bf, acc[tt], 0, 0, 0);
      }
    }
    float rsum[4] = {0.f, 0.f, 0.f, 0.f};
#pragma unroll
    for (int tt = 0; tt < 4; ++tt) {
      float wv = sW3[tt * 16 + l15];
#pragma unroll
      for (int j = 0; j < 4; ++j)
        rsum[j] = fmaf(fmaxf(acc[tt][j], 0.f), wv, rsum[j]);
    }
#pragma unroll
    for (int j = 0; j < 4; ++j) {
      rsum[j] += __shfl_xor(rsum[j], 1);
      rsum[j] += __shfl_xor(rsum[j], 2);
      rsum[j] += __shfl_xor(rsum[j], 4);
      rsum[j] += __shfl_xor(rsum[j], 8);
    }
    if (l15 == 0) {
      float b3 = sb3[0];
#pragma unroll
      for (int j = 0; j < 4; ++j)
        out[row0 + w * 16 + kgrp * 4 + j] = rsum[j] + b3;
    }
  }
}

extern "C" void kernel_launch(void* const* d_in, const int* in_sizes, int n_in,
                              void* d_out, int out_size, void* d_ws, size_t ws_size,
                              hipStream_t stream) {
  const float* x      = (const float*)d_in[0];
  const int*   ei     = (const int*)d_in[1];
  const float* orders = (const float*)d_in[2];
  const int*   batch  = (const int*)d_in[3];
  const float* gW1    = (const float*)d_in[4];
  const float* gb1    = (const float*)d_in[5];
  const float* gW2    = (const float*)d_in[6];
  const float* gb2    = (const float*)d_in[7];
  const float* gamma  = (const float*)d_in[8];
  const float* beta   = (const float*)d_in[9];
  const float* oW1    = (const float*)d_in[10];
  const float* ob1    = (const float*)d_in[11];
  const float* oW2    = (const float*)d_in[12];
  const float* ob2    = (const float*)d_in[13];
  const float* sW1    = (const float*)d_in[14];
  const float* sb1    = (const float*)d_in[15];
  const float* sW2    = (const float*)d_in[16];
  const float* sb2    = (const float*)d_in[17];
  const float* sW3    = (const float*)d_in[18];
  const float* sb3    = (const float*)d_in[19];
  float* out = (float*)d_out;

  char* ws = (char*)d_ws;
  _Float16* xh    = (_Float16*)ws;                // x fp16        [NN,128]
  _Float16* bufAh = xh + NH;                      // z fp16        [NN,128]
  _Float16* bufCh = bufAh + NH;                   // z2 fp16       [NN,128]
  float* accum  = (float*)(bufCh + NH);           // 256 (reduced stats)
  float* accum2 = accum + 256;                    // NSUB*256 sub-accumulators
  float* ssum   = accum2 + NSUB * 256;            // 256*128
  float* smean  = ssum + NB * HD;                 // 256*128
  float* smax   = smean + NB * HD;                // 256*128
  unsigned int* smaxU = (unsigned int*)(smax + NB * HD);  // 256*128
  float* gpart = (float*)(smaxU + NB * HD);       // 256*128
  int* rowptr = (int*)(gpart + NB * HD);          // NN
  int* col    = rowptr + NN;                      // NE
  unsigned int* binned = (unsigned int*)(col + NE);  // NE
  int* bucketTotal = (int*)(binned + NE);         // 256
  int* bucketBase  = bucketTotal + NBUCK;         // 257
  int* cursor      = bucketBase + NBUCK + 1;      // 256
  _Float16* Wp  = (_Float16*)(cursor + NBUCK);    // 3*2*16384 fp16 (GIN)
  _Float16* Wh  = Wp + 3 * 32768;                 // 45056 fp16 (head)

  // ---- CSR build (by dst): two-level locality-aware counting sort ----
  hipMemsetAsync(bucketTotal, 0, NBUCK * sizeof(int), stream);
  bucket_count<<<NCHUNK, 256, 0, stream>>>(ei, bucketTotal);
  bucket_scan<<<1, NBUCK, 0, stream>>>(bucketTotal, bucketBase, cursor);
  bucket_scatter<<<NCHUNK, 256, 0, stream>>>(ei, cursor, binned);
  bucket_csr<<<NBUCK, 256, 0, stream>>>(binned, bucketBase, rowptr, col);

  // ---- pack weights + convert x, once ----
  pack_w_kernel<<<48, 256, 0, stream>>>(gW1, gW2, Wp);
  pack_head_kernel<<<22, 256, 0, stream>>>(oW1, oW2, sW1, sW2, Wh);
  f32to16_kernel<<<(int)(NH / 8 + 255) / 256, 256, 0, stream>>>(x, xh);

  const int LAYER_GRID = (NN + 63) / 64;
  for (int l = 0; l < 3; ++l) {
    if (l == 0)
      gather_kernel<false, false><<<GATHER_GRID, 256, 0, stream>>>(
          xh, rowptr, col, accum, gamma, beta, bufAh);
    else
      gather_kernel<true, true><<<GATHER_GRID, 256, 0, stream>>>(
          bufCh, rowptr, col, accum, gamma + (l - 1) * 128, beta + (l - 1) * 128, bufAh);
    hipMemsetAsync(accum2, 0, NSUB * 256 * sizeof(float), stream);
    fused_layer<<<LAYER_GRID, 256, 0, stream>>>(
        bufAh, Wp + (long)l * 32768, gb1 + l * 128, gb2 + l * 128, bufCh, accum2);
    bn_reduce<<<1, 256, 0, stream>>>(accum2, accum);
  }

  // ---- 3-phase pooling (BN of last layer fused into partial) ----
  pool_init<<<128, 256, 0, stream>>>(ssum, smaxU);
  pool_partial<<<POOL_GRID, 128, 0, stream>>>(bufCh, accum, gamma + 2 * 128, beta + 2 * 128,
                                              batch, ssum, smaxU);
  pool_final<<<NB, 128, 0, stream>>>(batch, ssum, smaxU, smean, smax);

  // ---- head: hoisted graph part + per-order MFMA chain ----
  gpart_kernel<<<NB, 128, 0, stream>>>(smean, smax, ssum, sW1, sb1, gpart);
  head_mfma<<<NB, 128, 0, stream>>>(orders, Wh, ob1, ob2, gpart, sb2, sW3, sb3, out);
}